// Round 17
// baseline (222.383 us; speedup 1.0000x reference)
//
#include <hip/hip_runtime.h>
#include <math.h>

#define BB 4
#define CC 64
#define TT 128
#define QQ 128
#define KK 8
#define HH 128
#define NN 512
#define LL 121
#define LPAD 135

typedef unsigned short ushort;
typedef __attribute__((ext_vector_type(8))) short short8;
typedef __attribute__((ext_vector_type(4))) float f32x4;
typedef __attribute__((ext_vector_type(4))) float float4v;

#define GLP(p) ((const __attribute__((address_space(1))) void*)(p))
#define LDP(p) ((__attribute__((address_space(3))) void*)(p))

__device__ __forceinline__ ushort f2bf(float x) {
  unsigned u = __float_as_uint(x);
  unsigned r = (u + 0x7FFFu + ((u >> 16) & 1u)) >> 16;
  return (ushort)r;
}

// ---- merged prep: LayerNorm->xT, fragment-layout weights, zero page ----
// Bg: GEMM B in MFMA-fragment order [jblk 64][ks 8][s 2][lk 4][jr 16][e 8]
//     value = W[dir][(c*8+ks)*512 + quad*128 + h], c = s*32+lk*8+e,
//     j = jblk*16+jr -> dir=j>>9, t=j&511, h=(t>>7)*32+((t>>6)&1)*16+(t&15),
//     quad=(t>>4)&3.  A wave's fragment-group read = 1 KB contiguous.
// Bc2: conv B in fragment order [win 32][s 2][lk 4][c 64][e 8]
//     value = ctw[j2h*(CC*KK) + c*KK + kk], j2h = jh*128+sub*64+(s*4+lk)*8+e,
//     win = kk*4 + jh*2 + sub.
__global__ __launch_bounds__(256)
void prep_all(const float* __restrict__ f, const float* __restrict__ gamma,
              const float* __restrict__ beta, const float* __restrict__ wf,
              const float* __restrict__ wb, const float* __restrict__ ctw,
              ushort* __restrict__ xT, ushort* __restrict__ Bg,
              ushort* __restrict__ Bc2, ushort* __restrict__ zpage) {
  int bid = blockIdx.x, tid = threadIdx.x;
  if (bid < 256) {                       // --- LayerNorm -> xT[n][q][c] bf16
    int p = bid * 256 + tid;
    int q = p & (QQ - 1);
    int t = (p >> 7) & (TT - 1);
    int b = p >> 14;
    const float* base = f + (size_t)b * CC * TT * QQ + (size_t)t * QQ + q;
    float v[64];
#pragma unroll
    for (int c = 0; c < 64; ++c) v[c] = base[(size_t)c * TT * QQ];
    float s = 0.f, s2 = 0.f;
#pragma unroll
    for (int c = 0; c < 64; ++c) { s += v[c]; s2 += v[c] * v[c]; }
    float mu = s * (1.f / CC);
    float var = s2 * (1.f / CC) - mu * mu;
    float rs = rsqrtf(var + 1e-5f);
    int n = b * TT + t;
    ushort* dst = xT + (size_t)n * (CC * QQ) + (size_t)q * CC;
#pragma unroll
    for (int v8 = 0; v8 < 8; ++v8) {
      short8 ov;
#pragma unroll
      for (int e = 0; e < 8; ++e) {
        int c = v8 * 8 + e;
        ov[e] = (short)f2bf((v[c] - mu) * rs * gamma[c] + beta[c]);
      }
      *(short8*)(dst + v8 * 8) = ov;
    }
  } else if (bid < 2816) {               // --- Bg / Bc2 fragment transforms
    int idx = (bid - 256) * 256 + tid;
    if (idx < 524288) {
      int jblk = idx >> 13, r1 = idx & 8191;
      int ks = r1 >> 10, r2 = r1 & 1023;
      int s = r2 >> 9, r3 = r2 & 511;
      int lk = r3 >> 7, r4 = r3 & 127;
      int jr = r4 >> 3, e = r4 & 7;
      int j = jblk * 16 + jr;
      int c = s * 32 + lk * 8 + e;
      int dir = j >> 9, t = j & 511;
      int h = (t >> 7) * 32 + ((t >> 6) & 1) * 16 + (t & 15);
      int quad = (t >> 4) & 3;
      const float* w = dir ? wb : wf;
      Bg[idx] = f2bf(w[(size_t)(c * 8 + ks) * 512 + quad * 128 + h]);
    } else {
      int i2 = idx - 524288;             // 131072
      int win = i2 >> 12, r1 = i2 & 4095;
      int s = r1 >> 11, r2 = r1 & 2047;
      int lk = r2 >> 9, r3 = r2 & 511;
      int c = r3 >> 3, e = r3 & 7;
      int jo = (s * 4 + lk) * 8 + e;
      int kk = win >> 2, jh = (win >> 1) & 1, sub = win & 1;
      int j2h = jh * 128 + sub * 64 + jo;
      Bc2[i2] = f2bf(ctw[(size_t)j2h * (CC * KK) + c * KK + kk]);
    }
  } else {                               // --- zero page (512 B)
    if (tid < 128) ((unsigned*)zpage)[tid] = 0u;
  }
}

// ---- fused MFMA GEMM, BM=128 x BN=256, 4 waves 1Mx4N ----
// A = sliding window over xT rows, staged ONCE into Hs (18.4 KB LDS).
// B fragments loaded DIRECTLY from global (Bg fragment layout, L2-resident,
// 1 KB/wave coalesced) -> ZERO barriers in the K-loop, no B staging.
// Epilogue: wave-local in-register scan + 8 shuffles (unchanged).
__global__ __launch_bounds__(256, 2)
void gemm_mfma(const ushort* __restrict__ xT, const ushort* __restrict__ Bg,
               const float* __restrict__ b_fwd, const float* __restrict__ b_bwd,
               ushort* __restrict__ hp, int n0) {
  __shared__ __align__(16) ushort Hs[144 * 64];   // 18,432 B (A window)

  int tid = threadIdx.x;
  int nl = blockIdx.y;
  int r0 = blockIdx.x * 256;
  int lane = tid & 63, w = tid >> 6;
  int lrow = lane & 15, lk = lane >> 4;
  f32x4 acc[8][4] = {};
  const ushort* xTn = xT + (size_t)(n0 + nl) * (CC * QQ);

  // ---- stage A window ONCE: xT rows 0..134 (rows 135..143 clamped slop) ----
#pragma unroll
  for (int i = 0; i < 4; ++i) {
    int p = i * 256 + tid;
    int row = p >> 3, s3 = p & 7;
    int key = ((row >> 3) ^ row) & 7;
    const ushort* g = xTn + (size_t)row * CC + (s3 ^ key) * 8;
    ushort* l = &Hs[(size_t)(i * 256 + (tid & 192)) * 8];
    __builtin_amdgcn_global_load_lds(GLP(g), LDP(l), 16, 0, 0);
  }
  if (tid < 128) {                            // wave-uniform (waves 0,1 only)
    int p = 1024 + tid;
    int row = p >> 3, s3 = p & 7;
    int srow = row < 135 ? row : 134;         // keep reads in-bounds
    int key = ((row >> 3) ^ row) & 7;
    const ushort* g = xTn + (size_t)srow * CC + (s3 ^ key) * 8;
    ushort* l = &Hs[(size_t)(1024 + (tid & 64)) * 8];
    __builtin_amdgcn_global_load_lds(GLP(g), LDP(l), 16, 0, 0);
  }
  __syncthreads();

  int RLb = ((lrow & 0x0C) << 3) | (lrow & 3);
  // per-lane B base: jblk = blockIdx.x*16 + w*4 + nn
  // Bg strides (ushorts): jblk=8192, ks=1024, s=512, lk=128, jr=8.
  const ushort* Bw = Bg + ((size_t)(blockIdx.x * 16 + w * 4) * 8192)
                   + lk * 128 + lrow * 8;
#pragma unroll
  for (int ks = 0; ks < 8; ++ks) {
#pragma unroll
    for (int s = 0; s < 2; ++s) {
      short8 a[8], b[4];
#pragma unroll
      for (int nn = 0; nn < 4; ++nn)
        b[nn] = *(const short8*)&Bw[(size_t)nn * 8192 + ks * 1024 + s * 512];
#pragma unroll
      for (int m = 0; m < 8; ++m) {
        int R = RLb + m * 4 + ks;             // Hs row for MFMA-row m*16+lrow
        int key = ((R >> 3) ^ R) & 7;
        int slot = (s * 4 + lk) ^ key;
        a[m] = *(const short8*)&Hs[R * 64 + slot * 8];
      }
#pragma unroll
      for (int m = 0; m < 8; ++m)
#pragma unroll
        for (int nn = 0; nn < 4; ++nn)
          acc[m][nn] = __builtin_amdgcn_mfma_f32_16x16x32_bf16(
              a[m], b[nn], acc[m][nn], 0, 0, 0);
    }
  }

  // ---- epilogue: wave-local scan, no barriers ----
  int dirf = r0 >> 9;
  int hgroup = ((r0 & 511) >> 7) + (w >> 1);
  int h = hgroup * 32 + (w & 1) * 16 + lrow;
  const float* bias = dirf ? b_bwd : b_fwd;
  float bf = bias[h], br = bias[128 + h];

  // serial scan of this thread's 32 contiguous l, in-place into acc[m][0/1]
  float F = 1.f, U = 0.f;
  if (dirf == 0) {
#pragma unroll
    for (int m = 0; m < 8; ++m)
#pragma unroll
      for (int g = 0; g < 4; ++g) {
        int l = lk * 32 + m * 4 + g;
        float xt = acc[m][0][g], fp = acc[m][1][g];
        float fg = 1.f / (1.f + __expf(-(fp + bf)));
        float u = (1.f - fg) * xt;
        if (l > 120) { fg = 1.f; u = 0.f; }   // identity (kills garbage rows)
        U = fg * U + u;
        F = fg * F;
        acc[m][0][g] = F; acc[m][1][g] = U;
      }
  } else {
#pragma unroll
    for (int m = 7; m >= 0; --m)
#pragma unroll
      for (int g = 3; g >= 0; --g) {
        int l = lk * 32 + m * 4 + g;
        float xt = acc[m][0][g], fp = acc[m][1][g];
        float fg = 1.f / (1.f + __expf(-(fp + bf)));
        float u = (1.f - fg) * xt;
        if (l > 120) { fg = 1.f; u = 0.f; }
        U = fg * U + u;
        F = fg * F;
        acc[m][0][g] = F; acc[m][1][g] = U;
      }
  }
  // compose across lk chunks (full 128-l chain in this wave): 8 shuffles
  int e = dirf ? 3 - lk : lk;
  float lpU = 0.f;
#pragma unroll
  for (int j = 0; j < 4; ++j) {
    int jl = dirf ? 3 - j : j;
    float tF = __shfl(F, (jl << 4) + lrow);
    float tU = __shfl(U, (jl << 4) + lrow);
    if (j < e) lpU = tF * lpU + tU;
  }
  float cinit = lpU;
  // apply: c = U + F*cinit; h_out = r*tanh(c) + (1-r)*xp -> bf16 hp
  // UNCONDITIONAL stores: garbage l>120 land in hp rows 128..134 (never read;
  // conv redirects pad reads to the zero page).
  ushort* hpn = hp + (size_t)nl * LPAD * 256;
  int colbase = dirf * 128 + hgroup * 32 + (w & 1) * 16;
#pragma unroll
  for (int m = 0; m < 8; ++m) {
#pragma unroll
    for (int g = 0; g < 4; ++g) {
      int l = lk * 32 + m * 4 + g;
      float c = acc[m][1][g] + acc[m][0][g] * cinit;
      float rp = acc[m][2][g];
      float rg = 1.f / (1.f + __expf(-(rp + br)));
      float e2 = __expf(2.f * c);
      float th = (e2 - 1.f) / (e2 + 1.f);
      float ho = rg * th + (1.f - rg) * acc[m][3][g];
      hpn[(size_t)(l + 7) * 256 + colbase + lrow] = f2bf(ho);
    }
  }
}

// ---------------- ConvTranspose as MFMA GEMM, persistent-Hs, global-B ----------------
// hp[n] staged ONCE per j-half into Hs; B fragments read directly from Bc2
// (fragment layout, L2-resident). Only 2 barriers per j-half.
__global__ __launch_bounds__(256)
void conv_mfma(const ushort* __restrict__ hp, const ushort* __restrict__ Bc2,
               const ushort* __restrict__ zpage, const float* __restrict__ ctb,
               const float* __restrict__ feat, float* __restrict__ out, int n0) {
  __shared__ __align__(16) ushort Hs[144 * 128];   // 36,864 B
  int tid = threadIdx.x;
  int nl = blockIdx.x;
  int lane = tid & 63, w = tid >> 6;
  int wr0 = (w >> 1) * 64, wc0 = (w & 1) * 32;
  int lrow = lane & 15, lk = lane >> 4;
  f32x4 acc[4][2] = {};
  const ushort* hpn = hp + (size_t)nl * LPAD * 256;
  const ushort* Bcw = Bc2 + lk * 512 + (wc0 + lrow) * 8;

  for (int jh = 0; jh < 2; ++jh) {
    if (jh) __syncthreads();                 // all reads of prev Hs done
    // stage Hs: hp rows 0..143 of this j-half; rows outside [7,127] -> zeros
#pragma unroll
    for (int r = 0; r < 9; ++r) {
      int p = r * 256 + tid;
      int row = p >> 4, ds = p & 15;
      int cs = (ds & 8) | ((ds & 7) ^ (row & 7));
      const ushort* g = ((unsigned)(row - 7) <= 120u)
          ? hpn + (size_t)row * 256 + jh * 128 + cs * 8
          : zpage;
      ushort* l = &Hs[(size_t)(r * 256 + (tid & 192)) * 8];
      __builtin_amdgcn_global_load_lds(GLP(g), LDP(l), 16, 0, 0);
    }
    __syncthreads();
#pragma unroll
    for (int t = 0; t < 16; ++t) {
      int kk = t >> 1, sub = t & 1;
      int win = kk * 4 + jh * 2 + sub;
#pragma unroll
      for (int s = 0; s < 2; ++s) {
        short8 a[4], b[2];
#pragma unroll
        for (int nn = 0; nn < 2; ++nn)
          b[nn] = *(const short8*)&Bcw[(size_t)(win * 8 + s * 4) * 512 + nn * 128];
#pragma unroll
        for (int m = 0; m < 4; ++m) {
          int row = wr0 + m * 16 + lrow + 7 - kk;
          int slot = (sub * 8) | ((s * 4 + lk) ^ (row & 7));
          a[m] = *(const short8*)&Hs[row * 128 + slot * 8];
        }
#pragma unroll
        for (int m = 0; m < 4; ++m)
#pragma unroll
          for (int nn = 0; nn < 2; ++nn)
            acc[m][nn] = __builtin_amdgcn_mfma_f32_16x16x32_bf16(
                a[m], b[nn], acc[m][nn], 0, 0, 0);
      }
    }
  }
  int n = n0 + nl;
  int b = n >> 7, t = n & 127;
#pragma unroll
  for (int m = 0; m < 4; ++m) {
    int q0 = wr0 + m * 16 + lk * 4;
#pragma unroll
    for (int nn = 0; nn < 2; ++nn) {
      int c = wc0 + nn * 16 + lrow;
      size_t idx = (size_t)b * (CC * TT * QQ) + (size_t)c * (TT * QQ)
                 + (size_t)t * QQ + q0;
      float4v fv = *(const float4v*)&feat[idx];
      float cb = ctb[c];
      float4v ov;
#pragma unroll
      for (int g = 0; g < 4; ++g) ov[g] = acc[m][nn][g] + cb + fv[g];
      *(float4v*)&out[idx] = ov;
    }
  }
}

extern "C" void kernel_launch(void* const* d_in, const int* in_sizes, int n_in,
                              void* d_out, int out_size, void* d_ws, size_t ws_size,
                              hipStream_t stream) {
  const float* feat  = (const float*)d_in[0];
  const float* gamma = (const float*)d_in[1];
  const float* beta  = (const float*)d_in[2];
  const float* w_fwd = (const float*)d_in[3];
  const float* b_fwd = (const float*)d_in[4];
  const float* w_bwd = (const float*)d_in[5];
  const float* b_bwd = (const float*)d_in[6];
  const float* ct_w  = (const float*)d_in[7];
  const float* ct_b  = (const float*)d_in[8];
  float* out = (float*)d_out;

  char* wsb = (char*)d_ws;
  ushort* xT  = (ushort*)wsb;                         // 8,388,608 B (+1 KB pad)
  ushort* Bg  = (ushort*)(wsb + 8389632);             // 1,048,576 B
  ushort* Bc2 = (ushort*)(wsb + 9438208);             //   262,144 B
  ushort* zpg = (ushort*)(wsb + 9700352);             //       512 B
  size_t persist = 9700864;
  size_t per_n = 69120u;                              // hp only
  int NC = 4;
  for (int cand = 512; cand >= 4; cand >>= 1) {
    if (persist + (size_t)cand * per_n <= ws_size) { NC = cand; break; }
  }
  ushort* hpc = (ushort*)(wsb + persist);

  prep_all<<<dim3(2817), dim3(256), 0, stream>>>(feat, gamma, beta, w_fwd,
                                                 w_bwd, ct_w, xT, Bg, Bc2, zpg);

  for (int n0 = 0; n0 < NN; n0 += NC) {
    gemm_mfma<<<dim3(4, NC), dim3(256), 0, stream>>>(xT, Bg, b_fwd, b_bwd,
                                                     hpc, n0);
    conv_mfma<<<dim3(NC), dim3(256), 0, stream>>>(hpc, Bc2, zpg, ct_b, feat,
                                                  out, n0);
  }
}

// Round 18
// 119.159 us; speedup vs baseline: 1.8663x; 1.8663x over previous
//
#include <hip/hip_runtime.h>
#include <math.h>

#define BB 4
#define CC 64
#define TT 128
#define QQ 128
#define KK 8
#define HH 128
#define NN 512
#define LL 121
#define LPAD 135

typedef unsigned short ushort;
typedef __attribute__((ext_vector_type(8))) short short8;
typedef __attribute__((ext_vector_type(4))) float f32x4;
typedef __attribute__((ext_vector_type(4))) float float4v;

#define GLP(p) ((const __attribute__((address_space(1))) void*)(p))
#define LDP(p) ((__attribute__((address_space(3))) void*)(p))

__device__ __forceinline__ ushort f2bf(float x) {
  unsigned u = __float_as_uint(x);
  unsigned r = (u + 0x7FFFu + ((u >> 16) & 1u)) >> 16;
  return (ushort)r;
}

// ---- merged prep: LayerNorm->xT, fragment-layout weights, zero page ----
// Bg: GEMM B in MFMA-fragment order [jblk 64][ks 8][s 2][lk 4][jr 16][e 8]
// Bc2: conv B in fragment order [win 32][s 2][lk 4][c 64][e 8]
__global__ __launch_bounds__(256)
void prep_all(const float* __restrict__ f, const float* __restrict__ gamma,
              const float* __restrict__ beta, const float* __restrict__ wf,
              const float* __restrict__ wb, const float* __restrict__ ctw,
              ushort* __restrict__ xT, ushort* __restrict__ Bg,
              ushort* __restrict__ Bc2, ushort* __restrict__ zpage) {
  int bid = blockIdx.x, tid = threadIdx.x;
  if (bid < 256) {                       // --- LayerNorm -> xT[n][q][c] bf16
    int p = bid * 256 + tid;
    int q = p & (QQ - 1);
    int t = (p >> 7) & (TT - 1);
    int b = p >> 14;
    const float* base = f + (size_t)b * CC * TT * QQ + (size_t)t * QQ + q;
    float v[64];
#pragma unroll
    for (int c = 0; c < 64; ++c) v[c] = base[(size_t)c * TT * QQ];
    float s = 0.f, s2 = 0.f;
#pragma unroll
    for (int c = 0; c < 64; ++c) { s += v[c]; s2 += v[c] * v[c]; }
    float mu = s * (1.f / CC);
    float var = s2 * (1.f / CC) - mu * mu;
    float rs = rsqrtf(var + 1e-5f);
    int n = b * TT + t;
    ushort* dst = xT + (size_t)n * (CC * QQ) + (size_t)q * CC;
#pragma unroll
    for (int v8 = 0; v8 < 8; ++v8) {
      short8 ov;
#pragma unroll
      for (int e = 0; e < 8; ++e) {
        int c = v8 * 8 + e;
        ov[e] = (short)f2bf((v[c] - mu) * rs * gamma[c] + beta[c]);
      }
      *(short8*)(dst + v8 * 8) = ov;
    }
  } else if (bid < 2816) {               // --- Bg / Bc2 fragment transforms
    int idx = (bid - 256) * 256 + tid;
    if (idx < 524288) {
      int jblk = idx >> 13, r1 = idx & 8191;
      int ks = r1 >> 10, r2 = r1 & 1023;
      int s = r2 >> 9, r3 = r2 & 511;
      int lk = r3 >> 7, r4 = r3 & 127;
      int jr = r4 >> 3, e = r4 & 7;
      int j = jblk * 16 + jr;
      int c = s * 32 + lk * 8 + e;
      int dir = j >> 9, t = j & 511;
      int h = (t >> 7) * 32 + ((t >> 6) & 1) * 16 + (t & 15);
      int quad = (t >> 4) & 3;
      const float* w = dir ? wb : wf;
      Bg[idx] = f2bf(w[(size_t)(c * 8 + ks) * 512 + quad * 128 + h]);
    } else {
      int i2 = idx - 524288;             // 131072
      int win = i2 >> 12, r1 = i2 & 4095;
      int s = r1 >> 11, r2 = r1 & 2047;
      int lk = r2 >> 9, r3 = r2 & 511;
      int c = r3 >> 3, e = r3 & 7;
      int jo = (s * 4 + lk) * 8 + e;
      int kk = win >> 2, jh = (win >> 1) & 1, sub = win & 1;
      int j2h = jh * 128 + sub * 64 + jo;
      Bc2[i2] = f2bf(ctw[(size_t)j2h * (CC * KK) + c * KK + kk]);
    }
  } else {                               // --- zero page (512 B)
    if (tid < 128) ((unsigned*)zpage)[tid] = 0u;
  }
}

// ---- fused MFMA GEMM, BM=128 x BN=256, 4 waves 1Mx4N ----
// A = sliding window staged ONCE into Hs (18.4 KB LDS). B fragments loaded
// DIRECTLY from global (Bg, L2-resident, 1 KB/wave coalesced) -> zero K-loop
// barriers.  ks-loop is `#pragma unroll 1`: R17's full unroll let the
// scheduler hoist all 64 B-loads -> register spill (WRITE_SIZE 463 MB).
__global__ __launch_bounds__(256, 2)
void gemm_mfma(const ushort* __restrict__ xT, const ushort* __restrict__ Bg,
               const float* __restrict__ b_fwd, const float* __restrict__ b_bwd,
               ushort* __restrict__ hp, int n0) {
  __shared__ __align__(16) ushort Hs[144 * 64];   // 18,432 B (A window)

  int tid = threadIdx.x;
  int nl = blockIdx.y;
  int r0 = blockIdx.x * 256;
  int lane = tid & 63, w = tid >> 6;
  int lrow = lane & 15, lk = lane >> 4;
  f32x4 acc[8][4] = {};
  const ushort* xTn = xT + (size_t)(n0 + nl) * (CC * QQ);

  // ---- stage A window ONCE: xT rows 0..134 (rows 135..143 clamped slop) ----
#pragma unroll
  for (int i = 0; i < 4; ++i) {
    int p = i * 256 + tid;
    int row = p >> 3, s3 = p & 7;
    int key = ((row >> 3) ^ row) & 7;
    const ushort* g = xTn + (size_t)row * CC + (s3 ^ key) * 8;
    ushort* l = &Hs[(size_t)(i * 256 + (tid & 192)) * 8];
    __builtin_amdgcn_global_load_lds(GLP(g), LDP(l), 16, 0, 0);
  }
  if (tid < 128) {                            // wave-uniform (waves 0,1 only)
    int p = 1024 + tid;
    int row = p >> 3, s3 = p & 7;
    int srow = row < 135 ? row : 134;         // keep reads in-bounds
    int key = ((row >> 3) ^ row) & 7;
    const ushort* g = xTn + (size_t)srow * CC + (s3 ^ key) * 8;
    ushort* l = &Hs[(size_t)(1024 + (tid & 64)) * 8];
    __builtin_amdgcn_global_load_lds(GLP(g), LDP(l), 16, 0, 0);
  }
  __syncthreads();

  int RLb = ((lrow & 0x0C) << 3) | (lrow & 3);
  // Bg strides (ushorts): jblk=8192, ks=1024, s=512, lk=128, jr=8.
  const ushort* Bw = Bg + ((size_t)(blockIdx.x * 16 + w * 4) * 8192)
                   + lk * 128 + lrow * 8;
#pragma unroll 1
  for (int ks = 0; ks < 8; ++ks) {
#pragma unroll
    for (int s = 0; s < 2; ++s) {
      short8 a[8], b[4];
#pragma unroll
      for (int nn = 0; nn < 4; ++nn)
        b[nn] = *(const short8*)&Bw[(size_t)nn * 8192 + ks * 1024 + s * 512];
#pragma unroll
      for (int m = 0; m < 8; ++m) {
        int R = RLb + m * 4 + ks;             // Hs row for MFMA-row m*16+lrow
        int key = ((R >> 3) ^ R) & 7;
        int slot = (s * 4 + lk) ^ key;
        a[m] = *(const short8*)&Hs[R * 64 + slot * 8];
      }
#pragma unroll
      for (int m = 0; m < 8; ++m)
#pragma unroll
        for (int nn = 0; nn < 4; ++nn)
          acc[m][nn] = __builtin_amdgcn_mfma_f32_16x16x32_bf16(
              a[m], b[nn], acc[m][nn], 0, 0, 0);
    }
  }

  // ---- epilogue: wave-local scan, no barriers ----
  int dirf = r0 >> 9;
  int hgroup = ((r0 & 511) >> 7) + (w >> 1);
  int h = hgroup * 32 + (w & 1) * 16 + lrow;
  const float* bias = dirf ? b_bwd : b_fwd;
  float bf = bias[h], br = bias[128 + h];

  // serial scan of this thread's 32 contiguous l, in-place into acc[m][0/1]
  float F = 1.f, U = 0.f;
  if (dirf == 0) {
#pragma unroll
    for (int m = 0; m < 8; ++m)
#pragma unroll
      for (int g = 0; g < 4; ++g) {
        int l = lk * 32 + m * 4 + g;
        float xt = acc[m][0][g], fp = acc[m][1][g];
        float fg = 1.f / (1.f + __expf(-(fp + bf)));
        float u = (1.f - fg) * xt;
        if (l > 120) { fg = 1.f; u = 0.f; }   // identity (kills garbage rows)
        U = fg * U + u;
        F = fg * F;
        acc[m][0][g] = F; acc[m][1][g] = U;
      }
  } else {
#pragma unroll
    for (int m = 7; m >= 0; --m)
#pragma unroll
      for (int g = 3; g >= 0; --g) {
        int l = lk * 32 + m * 4 + g;
        float xt = acc[m][0][g], fp = acc[m][1][g];
        float fg = 1.f / (1.f + __expf(-(fp + bf)));
        float u = (1.f - fg) * xt;
        if (l > 120) { fg = 1.f; u = 0.f; }
        U = fg * U + u;
        F = fg * F;
        acc[m][0][g] = F; acc[m][1][g] = U;
      }
  }
  // compose across lk chunks (full 128-l chain in this wave): 8 shuffles
  int e = dirf ? 3 - lk : lk;
  float lpU = 0.f;
#pragma unroll
  for (int j = 0; j < 4; ++j) {
    int jl = dirf ? 3 - j : j;
    float tF = __shfl(F, (jl << 4) + lrow);
    float tU = __shfl(U, (jl << 4) + lrow);
    if (j < e) lpU = tF * lpU + tU;
  }
  float cinit = lpU;
  // apply: c = U + F*cinit; h_out = r*tanh(c) + (1-r)*xp -> bf16 hp
  // UNCONDITIONAL stores: garbage l>120 land in hp rows 128..134 (never read;
  // conv redirects pad reads to the zero page).
  ushort* hpn = hp + (size_t)nl * LPAD * 256;
  int colbase = dirf * 128 + hgroup * 32 + (w & 1) * 16;
#pragma unroll
  for (int m = 0; m < 8; ++m) {
#pragma unroll
    for (int g = 0; g < 4; ++g) {
      int l = lk * 32 + m * 4 + g;
      float c = acc[m][1][g] + acc[m][0][g] * cinit;
      float rp = acc[m][2][g];
      float rg = 1.f / (1.f + __expf(-(rp + br)));
      float e2 = __expf(2.f * c);
      float th = (e2 - 1.f) / (e2 + 1.f);
      float ho = rg * th + (1.f - rg) * acc[m][3][g];
      hpn[(size_t)(l + 7) * 256 + colbase + lrow] = f2bf(ho);
    }
  }
}

// ---------------- ConvTranspose as MFMA GEMM, persistent-Hs, global-B ----------------
// hp[n] staged ONCE per j-half into Hs; B fragments read directly from Bc2.
// t-loop is `#pragma unroll 1` (same hoist-spill hazard as gemm).
__global__ __launch_bounds__(256)
void conv_mfma(const ushort* __restrict__ hp, const ushort* __restrict__ Bc2,
               const ushort* __restrict__ zpage, const float* __restrict__ ctb,
               const float* __restrict__ feat, float* __restrict__ out, int n0) {
  __shared__ __align__(16) ushort Hs[144 * 128];   // 36,864 B
  int tid = threadIdx.x;
  int nl = blockIdx.x;
  int lane = tid & 63, w = tid >> 6;
  int wr0 = (w >> 1) * 64, wc0 = (w & 1) * 32;
  int lrow = lane & 15, lk = lane >> 4;
  f32x4 acc[4][2] = {};
  const ushort* hpn = hp + (size_t)nl * LPAD * 256;
  const ushort* Bcw = Bc2 + lk * 512 + (wc0 + lrow) * 8;

#pragma unroll 1
  for (int jh = 0; jh < 2; ++jh) {
    if (jh) __syncthreads();                 // all reads of prev Hs done
    // stage Hs: hp rows 0..143 of this j-half; rows outside [7,127] -> zeros
#pragma unroll
    for (int r = 0; r < 9; ++r) {
      int p = r * 256 + tid;
      int row = p >> 4, ds = p & 15;
      int cs = (ds & 8) | ((ds & 7) ^ (row & 7));
      const ushort* g = ((unsigned)(row - 7) <= 120u)
          ? hpn + (size_t)row * 256 + jh * 128 + cs * 8
          : zpage;
      ushort* l = &Hs[(size_t)(r * 256 + (tid & 192)) * 8];
      __builtin_amdgcn_global_load_lds(GLP(g), LDP(l), 16, 0, 0);
    }
    __syncthreads();
#pragma unroll 1
    for (int t = 0; t < 16; ++t) {
      int kk = t >> 1, sub = t & 1;
      int win = kk * 4 + jh * 2 + sub;
#pragma unroll
      for (int s = 0; s < 2; ++s) {
        short8 a[4], b[2];
#pragma unroll
        for (int nn = 0; nn < 2; ++nn)
          b[nn] = *(const short8*)&Bcw[(size_t)(win * 8 + s * 4) * 512 + nn * 128];
#pragma unroll
        for (int m = 0; m < 4; ++m) {
          int row = wr0 + m * 16 + lrow + 7 - kk;
          int slot = (sub * 8) | ((s * 4 + lk) ^ (row & 7));
          a[m] = *(const short8*)&Hs[row * 128 + slot * 8];
        }
#pragma unroll
        for (int m = 0; m < 4; ++m)
#pragma unroll
          for (int nn = 0; nn < 2; ++nn)
            acc[m][nn] = __builtin_amdgcn_mfma_f32_16x16x32_bf16(
                a[m], b[nn], acc[m][nn], 0, 0, 0);
      }
    }
  }
  int n = n0 + nl;
  int b = n >> 7, t = n & 127;
#pragma unroll
  for (int m = 0; m < 4; ++m) {
    int q0 = wr0 + m * 16 + lk * 4;
#pragma unroll
    for (int nn = 0; nn < 2; ++nn) {
      int c = wc0 + nn * 16 + lrow;
      size_t idx = (size_t)b * (CC * TT * QQ) + (size_t)c * (TT * QQ)
                 + (size_t)t * QQ + q0;
      float4v fv = *(const float4v*)&feat[idx];
      float cb = ctb[c];
      float4v ov;
#pragma unroll
      for (int g = 0; g < 4; ++g) ov[g] = acc[m][nn][g] + cb + fv[g];
      *(float4v*)&out[idx] = ov;
    }
  }
}

extern "C" void kernel_launch(void* const* d_in, const int* in_sizes, int n_in,
                              void* d_out, int out_size, void* d_ws, size_t ws_size,
                              hipStream_t stream) {
  const float* feat  = (const float*)d_in[0];
  const float* gamma = (const float*)d_in[1];
  const float* beta  = (const float*)d_in[2];
  const float* w_fwd = (const float*)d_in[3];
  const float* b_fwd = (const float*)d_in[4];
  const float* w_bwd = (const float*)d_in[5];
  const float* b_bwd = (const float*)d_in[6];
  const float* ct_w  = (const float*)d_in[7];
  const float* ct_b  = (const float*)d_in[8];
  float* out = (float*)d_out;

  char* wsb = (char*)d_ws;
  ushort* xT  = (ushort*)wsb;                         // 8,388,608 B (+1 KB pad)
  ushort* Bg  = (ushort*)(wsb + 8389632);             // 1,048,576 B
  ushort* Bc2 = (ushort*)(wsb + 9438208);             //   262,144 B
  ushort* zpg = (ushort*)(wsb + 9700352);             //       512 B
  size_t persist = 9700864;
  size_t per_n = 69120u;                              // hp only
  int NC = 4;
  for (int cand = 512; cand >= 4; cand >>= 1) {
    if (persist + (size_t)cand * per_n <= ws_size) { NC = cand; break; }
  }
  ushort* hpc = (ushort*)(wsb + persist);

  prep_all<<<dim3(2817), dim3(256), 0, stream>>>(feat, gamma, beta, w_fwd,
                                                 w_bwd, ct_w, xT, Bg, Bc2, zpg);

  for (int n0 = 0; n0 < NN; n0 += NC) {
    gemm_mfma<<<dim3(4, NC), dim3(256), 0, stream>>>(xT, Bg, b_fwd, b_bwd,
                                                     hpc, n0);
    conv_mfma<<<dim3(NC), dim3(256), 0, stream>>>(hpc, Bc2, zpg, ct_b, feat,
                                                  out, n0);
  }
}

// Round 19
// 115.101 us; speedup vs baseline: 1.9321x; 1.0353x over previous
//
#include <hip/hip_runtime.h>
#include <math.h>

#define BB 4
#define CC 64
#define TT 128
#define QQ 128
#define KK 8
#define HH 128
#define NN 512
#define LL 121
#define LPAD 135

typedef unsigned short ushort;
typedef __attribute__((ext_vector_type(8))) short short8;
typedef __attribute__((ext_vector_type(4))) float f32x4;
typedef __attribute__((ext_vector_type(4))) float float4v;

#define GLP(p) ((const __attribute__((address_space(1))) void*)(p))
#define LDP(p) ((__attribute__((address_space(3))) void*)(p))

__device__ __forceinline__ ushort f2bf(float x) {
  unsigned u = __float_as_uint(x);
  unsigned r = (u + 0x7FFFu + ((u >> 16) & 1u)) >> 16;
  return (ushort)r;
}

// ---- merged prep: LayerNorm->xT, fragment-layout weights, zero page ----
// Bg: GEMM B in MFMA-fragment order [jblk 64][ks 8][s 2][lk 4][jr 16][e 8]
// Bc2: conv B in fragment order [win 32][s 2][lk 4][c 64][e 8]
__global__ __launch_bounds__(256)
void prep_all(const float* __restrict__ f, const float* __restrict__ gamma,
              const float* __restrict__ beta, const float* __restrict__ wf,
              const float* __restrict__ wb, const float* __restrict__ ctw,
              ushort* __restrict__ xT, ushort* __restrict__ Bg,
              ushort* __restrict__ Bc2, ushort* __restrict__ zpage) {
  int bid = blockIdx.x, tid = threadIdx.x;
  if (bid < 256) {                       // --- LayerNorm -> xT[n][q][c] bf16
    int p = bid * 256 + tid;
    int q = p & (QQ - 1);
    int t = (p >> 7) & (TT - 1);
    int b = p >> 14;
    const float* base = f + (size_t)b * CC * TT * QQ + (size_t)t * QQ + q;
    float v[64];
#pragma unroll
    for (int c = 0; c < 64; ++c) v[c] = base[(size_t)c * TT * QQ];
    float s = 0.f, s2 = 0.f;
#pragma unroll
    for (int c = 0; c < 64; ++c) { s += v[c]; s2 += v[c] * v[c]; }
    float mu = s * (1.f / CC);
    float var = s2 * (1.f / CC) - mu * mu;
    float rs = rsqrtf(var + 1e-5f);
    int n = b * TT + t;
    ushort* dst = xT + (size_t)n * (CC * QQ) + (size_t)q * CC;
#pragma unroll
    for (int v8 = 0; v8 < 8; ++v8) {
      short8 ov;
#pragma unroll
      for (int e = 0; e < 8; ++e) {
        int c = v8 * 8 + e;
        ov[e] = (short)f2bf((v[c] - mu) * rs * gamma[c] + beta[c]);
      }
      *(short8*)(dst + v8 * 8) = ov;
    }
  } else if (bid < 2816) {               // --- Bg / Bc2 fragment transforms
    int idx = (bid - 256) * 256 + tid;
    if (idx < 524288) {
      int jblk = idx >> 13, r1 = idx & 8191;
      int ks = r1 >> 10, r2 = r1 & 1023;
      int s = r2 >> 9, r3 = r2 & 511;
      int lk = r3 >> 7, r4 = r3 & 127;
      int jr = r4 >> 3, e = r4 & 7;
      int j = jblk * 16 + jr;
      int c = s * 32 + lk * 8 + e;
      int dir = j >> 9, t = j & 511;
      int h = (t >> 7) * 32 + ((t >> 6) & 1) * 16 + (t & 15);
      int quad = (t >> 4) & 3;
      const float* w = dir ? wb : wf;
      Bg[idx] = f2bf(w[(size_t)(c * 8 + ks) * 512 + quad * 128 + h]);
    } else {
      int i2 = idx - 524288;             // 131072
      int win = i2 >> 12, r1 = i2 & 4095;
      int s = r1 >> 11, r2 = r1 & 2047;
      int lk = r2 >> 9, r3 = r2 & 511;
      int c = r3 >> 3, e = r3 & 7;
      int jo = (s * 4 + lk) * 8 + e;
      int kk = win >> 2, jh = (win >> 1) & 1, sub = win & 1;
      int j2h = jh * 128 + sub * 64 + jo;
      Bc2[i2] = f2bf(ctw[(size_t)j2h * (CC * KK) + c * KK + kk]);
    }
  } else {                               // --- zero page (512 B)
    if (tid < 128) ((unsigned*)zpage)[tid] = 0u;
  }
}

// ---- fused MFMA GEMM, BM=128 x BN=256, 4 waves 1Mx4N ----
// A = sliding window staged ONCE into Hs (18.4 KB LDS). B fragments loaded
// DIRECTLY from global (Bg, L2-resident) -> zero K-loop barriers.
// ks-loop `#pragma unroll 1` (full unroll spills: R17). T5 setprio around
// MFMA cluster (waves are phase-independent -> attn regime, m191).
__global__ __launch_bounds__(256, 2)
void gemm_mfma(const ushort* __restrict__ xT, const ushort* __restrict__ Bg,
               const float* __restrict__ b_fwd, const float* __restrict__ b_bwd,
               ushort* __restrict__ hp, int n0) {
  __shared__ __align__(16) ushort Hs[144 * 64];   // 18,432 B (A window)

  int tid = threadIdx.x;
  int nl = blockIdx.y;
  int r0 = blockIdx.x * 256;
  int lane = tid & 63, w = tid >> 6;
  int lrow = lane & 15, lk = lane >> 4;
  f32x4 acc[8][4] = {};
  const ushort* xTn = xT + (size_t)(n0 + nl) * (CC * QQ);

  // ---- stage A window ONCE: xT rows 0..134 (rows 135..143 clamped slop) ----
#pragma unroll
  for (int i = 0; i < 4; ++i) {
    int p = i * 256 + tid;
    int row = p >> 3, s3 = p & 7;
    int key = ((row >> 3) ^ row) & 7;
    const ushort* g = xTn + (size_t)row * CC + (s3 ^ key) * 8;
    ushort* l = &Hs[(size_t)(i * 256 + (tid & 192)) * 8];
    __builtin_amdgcn_global_load_lds(GLP(g), LDP(l), 16, 0, 0);
  }
  if (tid < 128) {                            // wave-uniform (waves 0,1 only)
    int p = 1024 + tid;
    int row = p >> 3, s3 = p & 7;
    int srow = row < 135 ? row : 134;         // keep reads in-bounds
    int key = ((row >> 3) ^ row) & 7;
    const ushort* g = xTn + (size_t)srow * CC + (s3 ^ key) * 8;
    ushort* l = &Hs[(size_t)(1024 + (tid & 64)) * 8];
    __builtin_amdgcn_global_load_lds(GLP(g), LDP(l), 16, 0, 0);
  }
  __syncthreads();

  int RLb = ((lrow & 0x0C) << 3) | (lrow & 3);
  // Bg strides (ushorts): jblk=8192, ks=1024, s=512, lk=128, jr=8.
  const ushort* Bw = Bg + ((size_t)(blockIdx.x * 16 + w * 4) * 8192)
                   + lk * 128 + lrow * 8;
#pragma unroll 1
  for (int ks = 0; ks < 8; ++ks) {
#pragma unroll
    for (int s = 0; s < 2; ++s) {
      short8 a[8], b[4];
#pragma unroll
      for (int nn = 0; nn < 4; ++nn)
        b[nn] = *(const short8*)&Bw[(size_t)nn * 8192 + ks * 1024 + s * 512];
#pragma unroll
      for (int m = 0; m < 8; ++m) {
        int R = RLb + m * 4 + ks;             // Hs row for MFMA-row m*16+lrow
        int key = ((R >> 3) ^ R) & 7;
        int slot = (s * 4 + lk) ^ key;
        a[m] = *(const short8*)&Hs[R * 64 + slot * 8];
      }
      __builtin_amdgcn_s_setprio(1);
#pragma unroll
      for (int m = 0; m < 8; ++m)
#pragma unroll
        for (int nn = 0; nn < 4; ++nn)
          acc[m][nn] = __builtin_amdgcn_mfma_f32_16x16x32_bf16(
              a[m], b[nn], acc[m][nn], 0, 0, 0);
      __builtin_amdgcn_s_setprio(0);
    }
  }

  // ---- epilogue: wave-local scan, no barriers ----
  int dirf = r0 >> 9;
  int hgroup = ((r0 & 511) >> 7) + (w >> 1);
  int h = hgroup * 32 + (w & 1) * 16 + lrow;
  const float* bias = dirf ? b_bwd : b_fwd;
  float bf = bias[h], br = bias[128 + h];

  // serial scan of this thread's 32 contiguous l, in-place into acc[m][0/1]
  float F = 1.f, U = 0.f;
  if (dirf == 0) {
#pragma unroll
    for (int m = 0; m < 8; ++m)
#pragma unroll
      for (int g = 0; g < 4; ++g) {
        int l = lk * 32 + m * 4 + g;
        float xt = acc[m][0][g], fp = acc[m][1][g];
        float fg = 1.f / (1.f + __expf(-(fp + bf)));
        float u = (1.f - fg) * xt;
        if (l > 120) { fg = 1.f; u = 0.f; }   // identity (kills garbage rows)
        U = fg * U + u;
        F = fg * F;
        acc[m][0][g] = F; acc[m][1][g] = U;
      }
  } else {
#pragma unroll
    for (int m = 7; m >= 0; --m)
#pragma unroll
      for (int g = 3; g >= 0; --g) {
        int l = lk * 32 + m * 4 + g;
        float xt = acc[m][0][g], fp = acc[m][1][g];
        float fg = 1.f / (1.f + __expf(-(fp + bf)));
        float u = (1.f - fg) * xt;
        if (l > 120) { fg = 1.f; u = 0.f; }
        U = fg * U + u;
        F = fg * F;
        acc[m][0][g] = F; acc[m][1][g] = U;
      }
  }
  // compose across lk chunks (full 128-l chain in this wave): 8 shuffles
  int e = dirf ? 3 - lk : lk;
  float lpU = 0.f;
#pragma unroll
  for (int j = 0; j < 4; ++j) {
    int jl = dirf ? 3 - j : j;
    float tF = __shfl(F, (jl << 4) + lrow);
    float tU = __shfl(U, (jl << 4) + lrow);
    if (j < e) lpU = tF * lpU + tU;
  }
  float cinit = lpU;
  // apply: c = U + F*cinit; h_out = r*tanh(c) + (1-r)*xp -> bf16 hp
  // UNCONDITIONAL stores: garbage l>120 land in hp rows 128..134 (never read;
  // conv redirects pad reads to the zero page).
  ushort* hpn = hp + (size_t)nl * LPAD * 256;
  int colbase = dirf * 128 + hgroup * 32 + (w & 1) * 16;
#pragma unroll
  for (int m = 0; m < 8; ++m) {
#pragma unroll
    for (int g = 0; g < 4; ++g) {
      int l = lk * 32 + m * 4 + g;
      float c = acc[m][1][g] + acc[m][0][g] * cinit;
      float rp = acc[m][2][g];
      float rg = 1.f / (1.f + __expf(-(rp + br)));
      float e2 = __expf(2.f * c);
      float th = (e2 - 1.f) / (e2 + 1.f);
      float ho = rg * th + (1.f - rg) * acc[m][3][g];
      hpn[(size_t)(l + 7) * 256 + colbase + lrow] = f2bf(ho);
    }
  }
}

// ---------------- ConvTranspose as MFMA GEMM, q-split persistent-Hs ----------------
// Block (qh, nl) computes q in [qh*64, qh*64+64). Hs = 71-row sliding window x
// all 256 j-cols (36.9 KB), staged ONCE (9 loads/thread). B from global Bc2.
// Grid 1024 blocks -> 4 blocks/CU.
__global__ __launch_bounds__(256, 4)
void conv_mfma(const ushort* __restrict__ hp, const ushort* __restrict__ Bc2,
               const ushort* __restrict__ zpage, const float* __restrict__ ctb,
               const float* __restrict__ feat, float* __restrict__ out, int n0) {
  __shared__ __align__(16) ushort Hs[72 * 256];    // 36,864 B
  int tid = threadIdx.x;
  int qh = blockIdx.x;                              // 0..1
  int nl = blockIdx.y;
  int lane = tid & 63, w = tid >> 6;
  int wr0 = (w >> 1) * 32, wc0 = (w & 1) * 32;
  int lrow = lane & 15, lk = lane >> 4;
  f32x4 acc[2][2] = {};
  const ushort* hpn = hp + (size_t)nl * LPAD * 256;
  const ushort* Bcw = Bc2 + lk * 512 + (wc0 + lrow) * 8;
  int qbase = qh * 64;

  // stage Hs rows qbase..qbase+71 (256 cols), XOR-swizzled within 8-chunk groups
#pragma unroll
  for (int r = 0; r < 9; ++r) {
    int p = r * 256 + tid;
    int row = p >> 5, ck = p & 31;                  // local row, dest chunk
    int cs = (ck & 24) | ((ck & 7) ^ (row & 7));    // source chunk
    int grow = qbase + row;
    const ushort* g = ((unsigned)(grow - 7) <= 120u)
        ? hpn + (size_t)grow * 256 + cs * 8
        : zpage;
    ushort* l = &Hs[(size_t)(r * 256 + (tid & 192)) * 8];
    __builtin_amdgcn_global_load_lds(GLP(g), LDP(l), 16, 0, 0);
  }
  __syncthreads();
#pragma unroll 1
  for (int t = 0; t < 32; ++t) {                    // win = t = kk*4+jh*2+sub
    int kk = t >> 2;
    int sh = (((t >> 1) & 1) << 4) | ((t & 1) << 3);
#pragma unroll
    for (int s = 0; s < 2; ++s) {
      short8 a[2], b[2];
#pragma unroll
      for (int nn = 0; nn < 2; ++nn)
        b[nn] = *(const short8*)&Bcw[(size_t)(t * 8 + s * 4) * 512 + nn * 128];
#pragma unroll
      for (int m = 0; m < 2; ++m) {
        int row = wr0 + m * 16 + lrow + 7 - kk;     // 0..70 (local)
        int slot = sh | ((s * 4 + lk) ^ (row & 7));
        a[m] = *(const short8*)&Hs[row * 256 + slot * 8];
      }
#pragma unroll
      for (int m = 0; m < 2; ++m)
#pragma unroll
        for (int nn = 0; nn < 2; ++nn)
          acc[m][nn] = __builtin_amdgcn_mfma_f32_16x16x32_bf16(
              a[m], b[nn], acc[m][nn], 0, 0, 0);
    }
  }
  int n = n0 + nl;
  int b = n >> 7, tt = n & 127;
#pragma unroll
  for (int m = 0; m < 2; ++m) {
    int q0 = qbase + wr0 + m * 16 + lk * 4;
#pragma unroll
    for (int nn = 0; nn < 2; ++nn) {
      int c = wc0 + nn * 16 + lrow;
      size_t idx = (size_t)b * (CC * TT * QQ) + (size_t)c * (TT * QQ)
                 + (size_t)tt * QQ + q0;
      float4v fv = *(const float4v*)&feat[idx];
      float cb = ctb[c];
      float4v ov;
#pragma unroll
      for (int g = 0; g < 4; ++g) ov[g] = acc[m][nn][g] + cb + fv[g];
      *(float4v*)&out[idx] = ov;
    }
  }
}

extern "C" void kernel_launch(void* const* d_in, const int* in_sizes, int n_in,
                              void* d_out, int out_size, void* d_ws, size_t ws_size,
                              hipStream_t stream) {
  const float* feat  = (const float*)d_in[0];
  const float* gamma = (const float*)d_in[1];
  const float* beta  = (const float*)d_in[2];
  const float* w_fwd = (const float*)d_in[3];
  const float* b_fwd = (const float*)d_in[4];
  const float* w_bwd = (const float*)d_in[5];
  const float* b_bwd = (const float*)d_in[6];
  const float* ct_w  = (const float*)d_in[7];
  const float* ct_b  = (const float*)d_in[8];
  float* out = (float*)d_out;

  char* wsb = (char*)d_ws;
  ushort* xT  = (ushort*)wsb;                         // 8,388,608 B (+1 KB pad)
  ushort* Bg  = (ushort*)(wsb + 8389632);             // 1,048,576 B
  ushort* Bc2 = (ushort*)(wsb + 9438208);             //   262,144 B
  ushort* zpg = (ushort*)(wsb + 9700352);             //       512 B
  size_t persist = 9700864;
  size_t per_n = 69120u;                              // hp only
  int NC = 4;
  for (int cand = 512; cand >= 4; cand >>= 1) {
    if (persist + (size_t)cand * per_n <= ws_size) { NC = cand; break; }
  }
  ushort* hpc = (ushort*)(wsb + persist);

  prep_all<<<dim3(2817), dim3(256), 0, stream>>>(feat, gamma, beta, w_fwd,
                                                 w_bwd, ct_w, xT, Bg, Bc2, zpg);

  for (int n0 = 0; n0 < NN; n0 += NC) {
    gemm_mfma<<<dim3(4, NC), dim3(256), 0, stream>>>(xT, Bg, b_fwd, b_bwd,
                                                     hpc, n0);
    conv_mfma<<<dim3(2, NC), dim3(256), 0, stream>>>(hpc, Bc2, zpg, ct_b, feat,
                                                     out, n0);
  }
}